// Round 5
// baseline (449.366 us; speedup 1.0000x reference)
//
#include <hip/hip_runtime.h>
#include <hip/hip_bf16.h>

#define B_   2
#define L_   2048
#define D_   2048
#define H_   32
#define HKV_ 8
#define HD_  64
#define G_   4
#define M_   4096   // B_*L_
#define NF_  3072   // fused QKV output width

typedef __attribute__((ext_vector_type(8))) short bf16x8;
typedef __attribute__((ext_vector_type(4))) float f32x4;

static __device__ __forceinline__ unsigned short f2bf(float f) {
  unsigned int u = __float_as_uint(f);
  unsigned int r = (u + 0x7FFFu + ((u >> 16) & 1u)) >> 16;
  return (unsigned short)r;
}
static __device__ __forceinline__ unsigned short f2bf_hw(float f) {
  __hip_bfloat16 h = __float2bfloat16(f);
  return *(unsigned short*)&h;
}

#define GLD16(g, l) __builtin_amdgcn_global_load_lds(                      \
    (const __attribute__((address_space(1))) void*)(g),                    \
    (__attribute__((address_space(3))) void*)(l), 16, 0, 0)

// ---------------- elementwise cast f32 -> bf16 (x4 vectorized) ----------------
__global__ void cast_bf16_kernel(const float* __restrict__ in,
                                 unsigned short* __restrict__ out, int n4) {
  int i = blockIdx.x * blockDim.x + threadIdx.x;
  if (i >= n4) return;
  float4 v = ((const float4*)in)[i];
  uint2 r;
  r.x = (unsigned int)f2bf(v.x) | ((unsigned int)f2bf(v.y) << 16);
  r.y = (unsigned int)f2bf(v.z) | ((unsigned int)f2bf(v.w) << 16);
  ((uint2*)out)[i] = r;
}

// ---------------- transpose+cast: src[K][N] f32 -> dst[N][K] bf16 ----------------
__global__ void transpose_cast_kernel(const float* __restrict__ src,
                                      unsigned short* __restrict__ dst,
                                      int K, int N) {
  __shared__ float tile[32][33];
  int k0 = blockIdx.y * 32, n0 = blockIdx.x * 32;
  int tx = threadIdx.x, ty = threadIdx.y;  // (32,8)
#pragma unroll
  for (int r = 0; r < 4; ++r)
    tile[ty * 4 + r][tx] = src[(size_t)(k0 + ty * 4 + r) * N + n0 + tx];
  __syncthreads();
#pragma unroll
  for (int r = 0; r < 4; ++r)
    dst[(size_t)(n0 + ty * 4 + r) * K + k0 + tx] = f2bf(tile[tx][ty * 4 + r]);
}

// ---------------- GEMM: C[M][N] f32 = A[M][K]bf16 * Bt[N][K]bf16 ----------------
// 128x128 tile, BK=32, 4 waves (2x2 of 64x64), m97 structure.
__global__ __launch_bounds__(256)
void gemm_bt_kernel(const unsigned short* __restrict__ A,
                    const unsigned short* __restrict__ Bt,
                    float* __restrict__ C, int M, int N, int K) {
  __shared__ unsigned short Al[128 * 32];
  __shared__ unsigned short Bl[128 * 32];
  const int tid = threadIdx.x;
  const int w = tid >> 6;
  const int l = tid & 63;
  const int row0 = blockIdx.y * 128;
  const int col0 = blockIdx.x * 128;
  const int wr = (w >> 1) * 64, wc = (w & 1) * 64;

  f32x4 acc[4][4];
#pragma unroll
  for (int m = 0; m < 4; ++m)
#pragma unroll
    for (int n = 0; n < 4; ++n) acc[m][n] = (f32x4){0.f, 0.f, 0.f, 0.f};

  const int srow = l >> 2;
  const int scol = (l & 3) * 8;
  const int fr = l & 15, fk = (l >> 4) * 8;
  const int nk = K / 32;

  for (int kt = 0; kt < nk; ++kt) {
    const int k0 = kt * 32;
#pragma unroll
    for (int t = 0; t < 2; ++t) {
      const int rr = (w * 2 + t) * 16 + srow;
      GLD16(A + (size_t)(row0 + rr) * K + k0 + scol, &Al[(w * 2 + t) * 512]);
      GLD16(Bt + (size_t)(col0 + rr) * K + k0 + scol, &Bl[(w * 2 + t) * 512]);
    }
    __syncthreads();
    bf16x8 af[4], bfr[4];
#pragma unroll
    for (int m = 0; m < 4; ++m)
      af[m] = *(const bf16x8*)&Al[(wr + m * 16 + fr) * 32 + fk];
#pragma unroll
    for (int n = 0; n < 4; ++n)
      bfr[n] = *(const bf16x8*)&Bl[(wc + n * 16 + fr) * 32 + fk];
#pragma unroll
    for (int m = 0; m < 4; ++m)
#pragma unroll
      for (int n = 0; n < 4; ++n)
        acc[m][n] = __builtin_amdgcn_mfma_f32_16x16x32_bf16(af[m], bfr[n], acc[m][n], 0, 0, 0);
    __syncthreads();
  }

  const int fq = l >> 4;
#pragma unroll
  for (int m = 0; m < 4; ++m)
#pragma unroll
    for (int n = 0; n < 4; ++n)
#pragma unroll
      for (int j = 0; j < 4; ++j) {
        int r = row0 + wr + m * 16 + fq * 4 + j;
        int c = col0 + wc + n * 16 + fr;
        C[(size_t)r * N + c] = acc[m][n][j];
      }
}

// ---------------- RoPE (float4-wide): src[M][3072]+col_off -> dst[B][nh][L][64] bf16 ----------------
__global__ void rope_kernel(const float* __restrict__ src,
                            const float* __restrict__ cosf,
                            const float* __restrict__ sinf,
                            unsigned short* __restrict__ dst, int nh, int col_off,
                            float scale, int total) {
  int idx = blockIdx.x * blockDim.x + threadIdx.x;
  if (idx >= total) return;
  int g = idx & 7;                  // group of 4 freqs (8 elements)
  int h = (idx >> 3) & (nh - 1);
  int row = idx / (nh << 3);
  int lpos = row & (L_ - 1);
  int b = row >> 11;
  const float* s = src + (size_t)row * NF_ + col_off + h * 64 + g * 8;
  float4 v0 = *(const float4*)s;
  float4 v1 = *(const float4*)(s + 4);
  float4 c4 = *(const float4*)(cosf + lpos * 32 + g * 4);
  float4 s4 = *(const float4*)(sinf + lpos * 32 + g * 4);
  float o0 = (v0.x * c4.x - v0.y * s4.x) * scale;
  float o1 = (v0.x * s4.x + v0.y * c4.x) * scale;
  float o2 = (v0.z * c4.y - v0.w * s4.y) * scale;
  float o3 = (v0.z * s4.y + v0.w * c4.y) * scale;
  float o4 = (v1.x * c4.z - v1.y * s4.z) * scale;
  float o5 = (v1.x * s4.z + v1.y * c4.z) * scale;
  float o6 = (v1.z * c4.w - v1.w * s4.w) * scale;
  float o7 = (v1.z * s4.w + v1.w * c4.w) * scale;
  uint4 r;
  r.x = (unsigned int)f2bf(o0) | ((unsigned int)f2bf(o1) << 16);
  r.y = (unsigned int)f2bf(o2) | ((unsigned int)f2bf(o3) << 16);
  r.z = (unsigned int)f2bf(o4) | ((unsigned int)f2bf(o5) << 16);
  r.w = (unsigned int)f2bf(o6) | ((unsigned int)f2bf(o7) << 16);
  *(uint4*)&dst[(((size_t)(b * nh + h)) * L_ + lpos) * 64 + g * 8] = r;
}

// ---------------- V transpose (LDS-tiled): qkv_f v-cols -> vT[B][HKV][64][L] bf16 ----------------
__global__ void cast_vT_kernel(const float* __restrict__ v,
                               unsigned short* __restrict__ vT) {
  __shared__ float tile[32][33];
  int l0 = blockIdx.x * 32, d0 = blockIdx.y * 32;
  int z = blockIdx.z;                 // b*8+hkv
  int b = z >> 3, hkv = z & 7;
  int tx = threadIdx.x, ty = threadIdx.y;  // (32,8)
  const float* src = v + (size_t)(b * L_) * NF_ + 2560 + hkv * 64;
#pragma unroll
  for (int r = 0; r < 4; ++r)
    tile[ty * 4 + r][tx] = src[(size_t)(l0 + ty * 4 + r) * NF_ + d0 + tx];
  __syncthreads();
  unsigned short* dst = vT + ((size_t)z * 64) * L_;
#pragma unroll
  for (int r = 0; r < 4; ++r)
    dst[(size_t)(d0 + ty * 4 + r) * L_ + l0 + tx] = f2bf(tile[tx][ty * 4 + r]);
}

// ---------------- Flash attention ----------------
// Grid (16,64) = 1024 blocks, XCD-chunk remapped (work = (lin%8)*128 + lin/8) so
// each XCD's L2 holds K/V for only 8 consecutive bh (2 (b,hkv) sets).
// Double-buffered K/V with issue-early staging + counted vmcnt(4): tile t+1's 4
// global_load_lds stay in flight while tile t computes; raw s_barrier (NOT
// __syncthreads -- that would re-insert a vmcnt(0) drain).
__global__ __launch_bounds__(256)
void attn_kernel(const unsigned short* __restrict__ Q,   // [B][H][L][64] (pre-scaled)
                 const unsigned short* __restrict__ Kt,  // [B][HKV][L][64]
                 const unsigned short* __restrict__ Vt,  // [B][HKV][64][L]
                 unsigned short* __restrict__ O) {       // [B*L][H*64]
  __shared__ unsigned short Kl[2][64 * 64];
  __shared__ unsigned short Vl[2][64 * 64];
  __shared__ unsigned short Pl[64 * 64];
  const int tid = threadIdx.x, w = tid >> 6, l = tid & 63;
  const int lin = blockIdx.y * 16 + blockIdx.x;
  const int work = ((lin & 7) << 7) + (lin >> 3);   // bijective XCD chunking
  const int bh = work >> 4, by = work & 15;
  const int b = bh >> 5, h = bh & 31;
  const int hkv = h >> 2;
  const int q0 = by * 128;
  const int fr = l & 15, hi = l >> 4;
  const int frx = fr & 7;

  const int srow = l >> 3;
  const int scole = ((l & 7) ^ srow) * 8;   // pre-swizzled global source col

  const unsigned short* kbase = Kt + ((size_t)(b * HKV_ + hkv)) * L_ * 64;
  const unsigned short* vbase = Vt + ((size_t)(b * HKV_ + hkv)) * 64 * L_;

  bf16x8 qf[2][2];
#pragma unroll
  for (int s = 0; s < 2; ++s) {
    const unsigned short* qb =
        Q + (((size_t)bh) * L_ + q0 + s * 64 + w * 16 + fr) * 64 + hi * 8;
    qf[s][0] = *(const bf16x8*)(qb);
    qf[s][1] = *(const bf16x8*)(qb + 32);
  }

  float m_i[2][4], l_p[2][4];
  f32x4 oacc[2][4];
#pragma unroll
  for (int s = 0; s < 2; ++s)
#pragma unroll
    for (int j = 0; j < 4; ++j) { m_i[s][j] = -1e30f; l_p[s][j] = 0.f; }
#pragma unroll
  for (int s = 0; s < 2; ++s)
#pragma unroll
    for (int nf = 0; nf < 4; ++nf) oacc[s][nf] = (f32x4){0.f, 0.f, 0.f, 0.f};

  const int nt = 2 * by + 2;

#define ASTAGE(kv0_, buf_) do {                                              \
    _Pragma("unroll")                                                        \
    for (int u_ = 0; u_ < 2; ++u_) {                                         \
      const int c_ = w * 2 + u_;                                             \
      const int rr_ = c_ * 8 + srow;                                         \
      GLD16(kbase + ((size_t)((kv0_) + rr_)) * 64 + scole,                   \
            &Kl[buf_][c_ * 512]);                                            \
      GLD16(vbase + ((size_t)rr_) * L_ + (kv0_) + scole,                     \
            &Vl[buf_][c_ * 512]);                                            \
    }                                                                        \
  } while (0)

  ASTAGE(0, 0);  // prologue: tile 0 -> buf 0 (4 loads/wave)

  for (int t = 0; t < nt; ++t) {
    const int buf = t & 1;
    if (t + 1 < nt) {
      ASTAGE((t + 1) * 64, buf ^ 1);                       // issue-early
      asm volatile("s_waitcnt vmcnt(4)" ::: "memory");     // tile t done, t+1 in flight
    } else {
      asm volatile("s_waitcnt vmcnt(0)" ::: "memory");
    }
    __builtin_amdgcn_s_barrier();

    const int kv0 = t * 64;
#pragma unroll
    for (int s = 0; s < 2; ++s) {
      const int dlim = 2 * by + s;
      if (t > dlim) continue;

      f32x4 sacc[4];
#pragma unroll
      for (int nf = 0; nf < 4; ++nf) sacc[nf] = (f32x4){0.f, 0.f, 0.f, 0.f};
      __builtin_amdgcn_s_setprio(1);
#pragma unroll
      for (int ks = 0; ks < 2; ++ks) {
#pragma unroll
        for (int nf = 0; nf < 4; ++nf) {
          bf16x8 kfrag = *(const bf16x8*)
              &Kl[buf][(nf * 16 + fr) * 64 + (((ks * 4 + hi) ^ frx) * 8)];
          sacc[nf] = __builtin_amdgcn_mfma_f32_16x16x32_bf16(qf[s][ks], kfrag, sacc[nf], 0, 0, 0);
        }
      }
      __builtin_amdgcn_s_setprio(0);

      if (t == dlim) {
        const int rbase = q0 + s * 64 + w * 16 + hi * 4;
#pragma unroll
        for (int nf = 0; nf < 4; ++nf)
#pragma unroll
          for (int j = 0; j < 4; ++j)
            if (kv0 + nf * 16 + fr > rbase + j) sacc[nf][j] = -1e30f;
      }

      float rowmax[4];
#pragma unroll
      for (int j = 0; j < 4; ++j) {
        float mx = fmaxf(fmaxf(sacc[0][j], sacc[1][j]),
                         fmaxf(sacc[2][j], sacc[3][j]));
        mx = fmaxf(mx, __shfl_xor(mx, 1));
        mx = fmaxf(mx, __shfl_xor(mx, 2));
        mx = fmaxf(mx, __shfl_xor(mx, 4));
        mx = fmaxf(mx, __shfl_xor(mx, 8));
        rowmax[j] = mx;
      }

      float g = rowmax[0] - m_i[s][0];
      g = fmaxf(g, rowmax[1] - m_i[s][1]);
      g = fmaxf(g, rowmax[2] - m_i[s][2]);
      g = fmaxf(g, rowmax[3] - m_i[s][3]);
      if (!__all(g <= 8.f)) {
#pragma unroll
        for (int j = 0; j < 4; ++j) {
          float mnew = fmaxf(m_i[s][j], rowmax[j]);
          float cr = exp2f(m_i[s][j] - mnew);
          m_i[s][j] = mnew;
          l_p[s][j] *= cr;
#pragma unroll
          for (int nf = 0; nf < 4; ++nf) oacc[s][nf][j] *= cr;
        }
      }

#pragma unroll
      for (int j = 0; j < 4; ++j) {
        const int prow = w * 16 + hi * 4 + j;
#pragma unroll
        for (int nf = 0; nf < 4; ++nf) {
          float p = exp2f(sacc[nf][j] - m_i[s][j]);
          l_p[s][j] += p;
          Pl[prow * 64 + (((nf * 2 + (fr >> 3)) ^ (prow & 7)) * 8) + frx] =
              f2bf_hw(p);
        }
      }

      __builtin_amdgcn_s_setprio(1);
#pragma unroll
      for (int ks = 0; ks < 2; ++ks) {
        bf16x8 pa = *(const bf16x8*)
            &Pl[(w * 16 + fr) * 64 + (((ks * 4 + hi) ^ frx) * 8)];
#pragma unroll
        for (int nf = 0; nf < 4; ++nf) {
          bf16x8 vfrag = *(const bf16x8*)
              &Vl[buf][(nf * 16 + fr) * 64 + (((ks * 4 + hi) ^ frx) * 8)];
          oacc[s][nf] = __builtin_amdgcn_mfma_f32_16x16x32_bf16(pa, vfrag, oacc[s][nf], 0, 0, 0);
        }
      }
      __builtin_amdgcn_s_setprio(0);
    }
    __builtin_amdgcn_s_barrier();   // guard buf reuse by next iteration's ASTAGE
  }
#undef ASTAGE

#pragma unroll
  for (int s = 0; s < 2; ++s)
#pragma unroll
    for (int j = 0; j < 4; ++j) {
      float lsum = l_p[s][j];
      lsum += __shfl_xor(lsum, 1);
      lsum += __shfl_xor(lsum, 2);
      lsum += __shfl_xor(lsum, 4);
      lsum += __shfl_xor(lsum, 8);
      float inv = 1.0f / lsum;
#pragma unroll
      for (int nf = 0; nf < 4; ++nf) {
        int qrow = q0 + s * 64 + w * 16 + hi * 4 + j;
        int d = nf * 16 + fr;
        O[((size_t)(b * L_ + qrow)) * 2048 + h * 64 + d] =
            f2bf_hw(oacc[s][nf][j] * inv);
      }
    }
}

extern "C" void kernel_launch(void* const* d_in, const int* in_sizes, int n_in,
                              void* d_out, int out_size, void* d_ws, size_t ws_size,
                              hipStream_t stream) {
  (void)in_sizes; (void)n_in; (void)out_size; (void)ws_size;
  const float* x  = (const float*)d_in[0];
  const float* wq = (const float*)d_in[1];
  const float* wk = (const float*)d_in[2];
  const float* wv = (const float*)d_in[3];
  const float* wo = (const float*)d_in[4];
  const float* fc = (const float*)d_in[5];
  const float* fs = (const float*)d_in[6];
  float* out = (float*)d_out;

  char* ws = (char*)d_ws;
  unsigned short* x_b  = (unsigned short*)(ws + 0);           // 16 MiB
  unsigned short* wT   = (unsigned short*)(ws + 16777216);    // 12 MiB [3072][2048]
  unsigned short* woT  = (unsigned short*)(ws + 29360128);    // 8 MiB
  float* qkv_f         = (float*)(ws + 37748736);             // 48 MiB [4096][3072]
  unsigned short* at_b = (unsigned short*)(ws + 37748736);    // aliases qkv_f (safe)
  unsigned short* q_b  = (unsigned short*)(ws + 88080384);    // 16 MiB
  unsigned short* k_b  = (unsigned short*)(ws + 104857600);   // 4 MiB
  unsigned short* vT_b = (unsigned short*)(ws + 109051904);   // 4 MiB

  const float qscale = 0.125f * 1.4426950408889634f;

  dim3 tb(32, 8);
  cast_bf16_kernel<<<8192, 256, 0, stream>>>(x, x_b, M_ * D_ / 4);
  transpose_cast_kernel<<<dim3(64, 64), tb, 0, stream>>>(wq, wT, 2048, 2048);
  transpose_cast_kernel<<<dim3(16, 64), tb, 0, stream>>>(wk, wT + (size_t)2048 * 2048, 2048, 512);
  transpose_cast_kernel<<<dim3(16, 64), tb, 0, stream>>>(wv, wT + (size_t)2560 * 2048, 2048, 512);
  transpose_cast_kernel<<<dim3(64, 64), tb, 0, stream>>>(wo, woT, 2048, 2048);

  gemm_bt_kernel<<<dim3(24, 32), 256, 0, stream>>>(x_b, wT, qkv_f, M_, NF_, 2048);

  rope_kernel<<<4096, 256, 0, stream>>>(qkv_f, fc, fs, q_b, 32, 0, qscale, M_ * 32 * 8);
  rope_kernel<<<1024, 256, 0, stream>>>(qkv_f, fc, fs, k_b, 8, 2048, 1.0f, M_ * 8 * 8);
  cast_vT_kernel<<<dim3(64, 2, 16), tb, 0, stream>>>(qkv_f, vT_b);

  attn_kernel<<<dim3(16, 64), 256, 0, stream>>>(q_b, k_b, vT_b, at_b);

  gemm_bt_kernel<<<dim3(16, 32), 256, 0, stream>>>(at_b, woT, out, M_, 2048, 2048);
}

// Round 8
// 403.367 us; speedup vs baseline: 1.1140x; 1.1140x over previous
//
#include <hip/hip_runtime.h>
#include <hip/hip_bf16.h>

#define B_   2
#define L_   2048
#define D_   2048
#define H_   32
#define HKV_ 8
#define HD_  64
#define G_   4
#define M_   4096   // B_*L_
#define NF_  3072   // fused QKV output width

typedef __attribute__((ext_vector_type(8))) short bf16x8;
typedef __attribute__((ext_vector_type(4))) float f32x4;

static __device__ __forceinline__ unsigned short f2bf(float f) {
  unsigned int u = __float_as_uint(f);
  unsigned int r = (u + 0x7FFFu + ((u >> 16) & 1u)) >> 16;
  return (unsigned short)r;
}
static __device__ __forceinline__ unsigned short f2bf_hw(float f) {
  __hip_bfloat16 h = __float2bfloat16(f);
  return *(unsigned short*)&h;
}

#define GLD16(g, l) __builtin_amdgcn_global_load_lds(                      \
    (const __attribute__((address_space(1))) void*)(g),                    \
    (__attribute__((address_space(3))) void*)(l), 16, 0, 0)

// ---------------- elementwise cast f32 -> bf16 (x4 vectorized) ----------------
__global__ void cast_bf16_kernel(const float* __restrict__ in,
                                 unsigned short* __restrict__ out, int n4) {
  int i = blockIdx.x * blockDim.x + threadIdx.x;
  if (i >= n4) return;
  float4 v = ((const float4*)in)[i];
  uint2 r;
  r.x = (unsigned int)f2bf(v.x) | ((unsigned int)f2bf(v.y) << 16);
  r.y = (unsigned int)f2bf(v.z) | ((unsigned int)f2bf(v.w) << 16);
  ((uint2*)out)[i] = r;
}

// ---------------- transpose+cast: src[K][N] f32 -> dst[N][K] bf16 ----------------
__global__ void transpose_cast_kernel(const float* __restrict__ src,
                                      unsigned short* __restrict__ dst,
                                      int K, int N) {
  __shared__ float tile[32][33];
  int k0 = blockIdx.y * 32, n0 = blockIdx.x * 32;
  int tx = threadIdx.x, ty = threadIdx.y;  // (32,8)
#pragma unroll
  for (int r = 0; r < 4; ++r)
    tile[ty * 4 + r][tx] = src[(size_t)(k0 + ty * 4 + r) * N + n0 + tx];
  __syncthreads();
#pragma unroll
  for (int r = 0; r < 4; ++r)
    dst[(size_t)(n0 + ty * 4 + r) * K + k0 + tx] = f2bf(tile[tx][ty * 4 + r]);
}

// ---------------- fused QKV weight transpose: wq/wk/wv -> wT[3072][2048] bf16 ----------------
__global__ void transpose_cast_qkv_kernel(const float* __restrict__ wq,
                                          const float* __restrict__ wk,
                                          const float* __restrict__ wv,
                                          unsigned short* __restrict__ dst) {
  __shared__ float tile[32][33];
  int n0 = blockIdx.x * 32, k0 = blockIdx.y * 32;
  const float* src;
  int ns, N;
  if (n0 < 2048)      { src = wq; ns = n0;        N = 2048; }
  else if (n0 < 2560) { src = wk; ns = n0 - 2048; N = 512; }
  else                { src = wv; ns = n0 - 2560; N = 512; }
  int tx = threadIdx.x, ty = threadIdx.y;  // (32,8)
#pragma unroll
  for (int r = 0; r < 4; ++r)
    tile[ty * 4 + r][tx] = src[(size_t)(k0 + ty * 4 + r) * N + ns + tx];
  __syncthreads();
#pragma unroll
  for (int r = 0; r < 4; ++r)
    dst[(size_t)(n0 + ty * 4 + r) * 2048 + k0 + tx] = f2bf(tile[tx][ty * 4 + r]);
}

// ---------------- GEMM: C[M][N] f32 = A[M][K]bf16 * Bt[N][K]bf16 ----------------
// 128x128 tile, BK=32, 4 waves (2x2 of 64x64), m97 structure.
__global__ __launch_bounds__(256)
void gemm_bt_kernel(const unsigned short* __restrict__ A,
                    const unsigned short* __restrict__ Bt,
                    float* __restrict__ C, int M, int N, int K) {
  __shared__ unsigned short Al[128 * 32];
  __shared__ unsigned short Bl[128 * 32];
  const int tid = threadIdx.x;
  const int w = tid >> 6;
  const int l = tid & 63;
  const int row0 = blockIdx.y * 128;
  const int col0 = blockIdx.x * 128;
  const int wr = (w >> 1) * 64, wc = (w & 1) * 64;

  f32x4 acc[4][4];
#pragma unroll
  for (int m = 0; m < 4; ++m)
#pragma unroll
    for (int n = 0; n < 4; ++n) acc[m][n] = (f32x4){0.f, 0.f, 0.f, 0.f};

  const int srow = l >> 2;
  const int scol = (l & 3) * 8;
  const int fr = l & 15, fk = (l >> 4) * 8;
  const int nk = K / 32;

  for (int kt = 0; kt < nk; ++kt) {
    const int k0 = kt * 32;
#pragma unroll
    for (int t = 0; t < 2; ++t) {
      const int rr = (w * 2 + t) * 16 + srow;
      GLD16(A + (size_t)(row0 + rr) * K + k0 + scol, &Al[(w * 2 + t) * 512]);
      GLD16(Bt + (size_t)(col0 + rr) * K + k0 + scol, &Bl[(w * 2 + t) * 512]);
    }
    __syncthreads();
    bf16x8 af[4], bfr[4];
#pragma unroll
    for (int m = 0; m < 4; ++m)
      af[m] = *(const bf16x8*)&Al[(wr + m * 16 + fr) * 32 + fk];
#pragma unroll
    for (int n = 0; n < 4; ++n)
      bfr[n] = *(const bf16x8*)&Bl[(wc + n * 16 + fr) * 32 + fk];
#pragma unroll
    for (int m = 0; m < 4; ++m)
#pragma unroll
      for (int n = 0; n < 4; ++n)
        acc[m][n] = __builtin_amdgcn_mfma_f32_16x16x32_bf16(af[m], bfr[n], acc[m][n], 0, 0, 0);
    __syncthreads();
  }

  const int fq = l >> 4;
#pragma unroll
  for (int m = 0; m < 4; ++m)
#pragma unroll
    for (int n = 0; n < 4; ++n)
#pragma unroll
      for (int j = 0; j < 4; ++j) {
        int r = row0 + wr + m * 16 + fq * 4 + j;
        int c = col0 + wc + n * 16 + fr;
        C[(size_t)r * N + c] = acc[m][n][j];
      }
}

// ---------------- RoPE (float4-wide): src[M][3072]+col_off -> dst[B][nh][L][64] bf16 ----------------
__global__ void rope_kernel(const float* __restrict__ src,
                            const float* __restrict__ cosf,
                            const float* __restrict__ sinf,
                            unsigned short* __restrict__ dst, int nh, int col_off,
                            float scale, int total) {
  int idx = blockIdx.x * blockDim.x + threadIdx.x;
  if (idx >= total) return;
  int g = idx & 7;                  // group of 4 freqs (8 elements)
  int h = (idx >> 3) & (nh - 1);
  int row = idx / (nh << 3);
  int lpos = row & (L_ - 1);
  int b = row >> 11;
  const float* s = src + (size_t)row * NF_ + col_off + h * 64 + g * 8;
  float4 v0 = *(const float4*)s;
  float4 v1 = *(const float4*)(s + 4);
  float4 c4 = *(const float4*)(cosf + lpos * 32 + g * 4);
  float4 s4 = *(const float4*)(sinf + lpos * 32 + g * 4);
  float o0 = (v0.x * c4.x - v0.y * s4.x) * scale;
  float o1 = (v0.x * s4.x + v0.y * c4.x) * scale;
  float o2 = (v0.z * c4.y - v0.w * s4.y) * scale;
  float o3 = (v0.z * s4.y + v0.w * c4.y) * scale;
  float o4 = (v1.x * c4.z - v1.y * s4.z) * scale;
  float o5 = (v1.x * s4.z + v1.y * c4.z) * scale;
  float o6 = (v1.z * c4.w - v1.w * s4.w) * scale;
  float o7 = (v1.z * s4.w + v1.w * c4.w) * scale;
  uint4 r;
  r.x = (unsigned int)f2bf(o0) | ((unsigned int)f2bf(o1) << 16);
  r.y = (unsigned int)f2bf(o2) | ((unsigned int)f2bf(o3) << 16);
  r.z = (unsigned int)f2bf(o4) | ((unsigned int)f2bf(o5) << 16);
  r.w = (unsigned int)f2bf(o6) | ((unsigned int)f2bf(o7) << 16);
  *(uint4*)&dst[(((size_t)(b * nh + h)) * L_ + lpos) * 64 + g * 8] = r;
}

// ---------------- V transpose (LDS-tiled): qkv_f v-cols -> vT[B][HKV][64][L] bf16 ----------------
__global__ void cast_vT_kernel(const float* __restrict__ v,
                               unsigned short* __restrict__ vT) {
  __shared__ float tile[32][33];
  int l0 = blockIdx.x * 32, d0 = blockIdx.y * 32;
  int z = blockIdx.z;                 // b*8+hkv
  int b = z >> 3, hkv = z & 7;
  int tx = threadIdx.x, ty = threadIdx.y;  // (32,8)
  const float* src = v + (size_t)(b * L_) * NF_ + 2560 + hkv * 64;
#pragma unroll
  for (int r = 0; r < 4; ++r)
    tile[ty * 4 + r][tx] = src[(size_t)(l0 + ty * 4 + r) * NF_ + d0 + tx];
  __syncthreads();
  unsigned short* dst = vT + ((size_t)z * 64) * L_;
#pragma unroll
  for (int r = 0; r < 4; ++r)
    dst[(size_t)(d0 + ty * 4 + r) * L_ + l0 + tx] = f2bf(tile[tx][ty * 4 + r]);
}

// ---------------- Flash attention ----------------
// Grid 1024 blocks; each block = PAIRED 64-row q-blocks {p, 31-p} of one (b,h)
// -> exactly 33 KV tiles/block (uniform causal load balance), run as one flat
// 33-job pipeline: double-buffered K/V, issue-early staging, counted vmcnt(4),
// raw s_barrier, XCD-chunked block remap. Compile-time half dispatch (no
// runtime-indexed register arrays).
__global__ __launch_bounds__(256)
void attn_kernel(const unsigned short* __restrict__ Q,   // [B][H][L][64] (pre-scaled)
                 const unsigned short* __restrict__ Kt,  // [B][HKV][L][64]
                 const unsigned short* __restrict__ Vt,  // [B][HKV][64][L]
                 unsigned short* __restrict__ O) {       // [B*L][H*64]
  __shared__ unsigned short Kl[2][64 * 64];
  __shared__ unsigned short Vl[2][64 * 64];
  __shared__ unsigned short Pl[64 * 64];
  const int tid = threadIdx.x, w = tid >> 6, l = tid & 63;
  const int lin = blockIdx.y * 16 + blockIdx.x;
  const int work = ((lin & 7) << 7) + (lin >> 3);   // bijective XCD chunking
  const int bh = work >> 4, p = work & 15;
  const int b = bh >> 5, h = bh & 31;
  const int hkv = h >> 2;
  const int byA = p, byB = 31 - p;                  // paired q-blocks (64 rows)
  const int q0A = byA * 64, q0B = byB * 64;
  const int fr = l & 15, hi = l >> 4;
  const int frx = fr & 7;

  const int srow = l >> 3;
  const int scole = ((l & 7) ^ srow) * 8;   // pre-swizzled global source col

  const unsigned short* kbase = Kt + ((size_t)(b * HKV_ + hkv)) * L_ * 64;
  const unsigned short* vbase = Vt + ((size_t)(b * HKV_ + hkv)) * 64 * L_;

  bf16x8 qf[2][2];
#pragma unroll
  for (int s = 0; s < 2; ++s) {
    const int qq0 = s ? q0B : q0A;
    const unsigned short* qb =
        Q + (((size_t)bh) * L_ + qq0 + w * 16 + fr) * 64 + hi * 8;
    qf[s][0] = *(const bf16x8*)(qb);
    qf[s][1] = *(const bf16x8*)(qb + 32);
  }

  float m_i[2][4], l_p[2][4];
  f32x4 oacc[2][4];
#pragma unroll
  for (int s = 0; s < 2; ++s)
#pragma unroll
    for (int j = 0; j < 4; ++j) { m_i[s][j] = -1e30f; l_p[s][j] = 0.f; }
#pragma unroll
  for (int s = 0; s < 2; ++s)
#pragma unroll
    for (int nf = 0; nf < 4; ++nf) oacc[s][nf] = (f32x4){0.f, 0.f, 0.f, 0.f};

#define ASTAGE(kv0_, buf_) do {                                              \
    _Pragma("unroll")                                                        \
    for (int u_ = 0; u_ < 2; ++u_) {                                         \
      const int c_ = w * 2 + u_;                                             \
      const int rr_ = c_ * 8 + srow;                                         \
      GLD16(kbase + ((size_t)((kv0_) + rr_)) * 64 + scole,                   \
            &Kl[buf_][c_ * 512]);                                            \
      GLD16(vbase + ((size_t)rr_) * L_ + (kv0_) + scole,                     \
            &Vl[buf_][c_ * 512]);                                            \
    }                                                                        \
  } while (0)

// one strip-tile of compute for compile-time half H_ (avoids runtime-indexed regs)
#define COMPUTE(H_) do {                                                     \
    const int qq0 = (H_) ? q0B : q0A;                                        \
    f32x4 sacc[4];                                                           \
    _Pragma("unroll")                                                        \
    for (int nf = 0; nf < 4; ++nf) sacc[nf] = (f32x4){0.f, 0.f, 0.f, 0.f};   \
    __builtin_amdgcn_s_setprio(1);                                           \
    _Pragma("unroll")                                                        \
    for (int ks = 0; ks < 2; ++ks) {                                         \
      _Pragma("unroll")                                                      \
      for (int nf = 0; nf < 4; ++nf) {                                       \
        bf16x8 kfrag = *(const bf16x8*)                                      \
            &Kl[buf][(nf * 16 + fr) * 64 + (((ks * 4 + hi) ^ frx) * 8)];     \
        sacc[nf] = __builtin_amdgcn_mfma_f32_16x16x32_bf16(                  \
            qf[H_][ks], kfrag, sacc[nf], 0, 0, 0);                           \
      }                                                                      \
    }                                                                        \
    __builtin_amdgcn_s_setprio(0);                                           \
    if (diag) {                                                              \
      const int rbase = qq0 + w * 16 + hi * 4;                               \
      _Pragma("unroll")                                                      \
      for (int nf = 0; nf < 4; ++nf)                                         \
        _Pragma("unroll")                                                    \
        for (int j = 0; j < 4; ++j)                                          \
          if (kv0 + nf * 16 + fr > rbase + j) sacc[nf][j] = -1e30f;          \
    }                                                                        \
    float rowmax[4];                                                         \
    _Pragma("unroll")                                                        \
    for (int j = 0; j < 4; ++j) {                                            \
      float mx = fmaxf(fmaxf(sacc[0][j], sacc[1][j]),                        \
                       fmaxf(sacc[2][j], sacc[3][j]));                       \
      mx = fmaxf(mx, __shfl_xor(mx, 1));                                     \
      mx = fmaxf(mx, __shfl_xor(mx, 2));                                     \
      mx = fmaxf(mx, __shfl_xor(mx, 4));                                     \
      mx = fmaxf(mx, __shfl_xor(mx, 8));                                     \
      rowmax[j] = mx;                                                        \
    }                                                                        \
    float g = rowmax[0] - m_i[H_][0];                                        \
    g = fmaxf(g, rowmax[1] - m_i[H_][1]);                                    \
    g = fmaxf(g, rowmax[2] - m_i[H_][2]);                                    \
    g = fmaxf(g, rowmax[3] - m_i[H_][3]);                                    \
    if (!__all(g <= 8.f)) {                                                  \
      _Pragma("unroll")                                                      \
      for (int j = 0; j < 4; ++j) {                                          \
        float mnew = fmaxf(m_i[H_][j], rowmax[j]);                           \
        float cr = exp2f(m_i[H_][j] - mnew);                                 \
        m_i[H_][j] = mnew;                                                   \
        l_p[H_][j] *= cr;                                                    \
        _Pragma("unroll")                                                    \
        for (int nf = 0; nf < 4; ++nf) oacc[H_][nf][j] *= cr;                \
      }                                                                      \
    }                                                                        \
    _Pragma("unroll")                                                        \
    for (int j = 0; j < 4; ++j) {                                            \
      const int prow = w * 16 + hi * 4 + j;                                  \
      _Pragma("unroll")                                                      \
      for (int nf = 0; nf < 4; ++nf) {                                       \
        float pv = exp2f(sacc[nf][j] - m_i[H_][j]);                          \
        l_p[H_][j] += pv;                                                    \
        Pl[prow * 64 + (((nf * 2 + (fr >> 3)) ^ (prow & 7)) * 8) + frx] =    \
            f2bf_hw(pv);                                                     \
      }                                                                      \
    }                                                                        \
    __builtin_amdgcn_s_setprio(1);                                           \
    _Pragma("unroll")                                                        \
    for (int ks = 0; ks < 2; ++ks) {                                         \
      bf16x8 pa = *(const bf16x8*)                                           \
          &Pl[(w * 16 + fr) * 64 + (((ks * 4 + hi) ^ frx) * 8)];             \
      _Pragma("unroll")                                                      \
      for (int nf = 0; nf < 4; ++nf) {                                       \
        bf16x8 vfrag = *(const bf16x8*)                                      \
            &Vl[buf][(nf * 16 + fr) * 64 + (((ks * 4 + hi) ^ frx) * 8)];     \
        oacc[H_][nf] = __builtin_amdgcn_mfma_f32_16x16x32_bf16(              \
            pa, vfrag, oacc[H_][nf], 0, 0, 0);                               \
      }                                                                      \
    }                                                                        \
    __builtin_amdgcn_s_setprio(0);                                           \
  } while (0)

  ASTAGE(0, 0);  // prologue: job 0 -> buf 0 (4 loads/wave)

  for (int job = 0; job <= 32; ++job) {
    const int buf = job & 1;
    const int half = (job > byA) ? 1 : 0;
    const int kv0 = (half ? (job - byA - 1) : job) * 64;
    const bool diag = (job == byA) || (job == 32);

    if (job < 32) {
      const int nxt_half = ((job + 1) > byA) ? 1 : 0;
      const int nxt_kv0 = (nxt_half ? (job - byA) : (job + 1)) * 64;
      ASTAGE(nxt_kv0, buf ^ 1);                            // issue-early
      asm volatile("s_waitcnt vmcnt(4)" ::: "memory");     // job's tile done
    } else {
      asm volatile("s_waitcnt vmcnt(0)" ::: "memory");
    }
    __builtin_amdgcn_s_barrier();

    if (half == 0) COMPUTE(0); else COMPUTE(1);

    __builtin_amdgcn_s_barrier();   // guard buf reuse by next job's ASTAGE
  }
#undef ASTAGE
#undef COMPUTE

#pragma unroll
  for (int s = 0; s < 2; ++s) {
    const int qq0 = s ? q0B : q0A;
#pragma unroll
    for (int j = 0; j < 4; ++j) {
      float lsum = l_p[s][j];
      lsum += __shfl_xor(lsum, 1);
      lsum += __shfl_xor(lsum, 2);
      lsum += __shfl_xor(lsum, 4);
      lsum += __shfl_xor(lsum, 8);
      float inv = 1.0f / lsum;
#pragma unroll
      for (int nf = 0; nf < 4; ++nf) {
        int qrow = qq0 + w * 16 + hi * 4 + j;
        int d = nf * 16 + fr;
        O[((size_t)(b * L_ + qrow)) * 2048 + h * 64 + d] =
            f2bf_hw(oacc[s][nf][j] * inv);
      }
    }
  }
}

extern "C" void kernel_launch(void* const* d_in, const int* in_sizes, int n_in,
                              void* d_out, int out_size, void* d_ws, size_t ws_size,
                              hipStream_t stream) {
  (void)in_sizes; (void)n_in; (void)out_size; (void)ws_size;
  const float* x  = (const float*)d_in[0];
  const float* wq = (const float*)d_in[1];
  const float* wk = (const float*)d_in[2];
  const float* wv = (const float*)d_in[3];
  const float* wo = (const float*)d_in[4];
  const float* fc = (const float*)d_in[5];
  const float* fs = (const float*)d_in[6];
  float* out = (float*)d_out;

  char* ws = (char*)d_ws;
  unsigned short* x_b  = (unsigned short*)(ws + 0);           // 16 MiB
  unsigned short* wT   = (unsigned short*)(ws + 16777216);    // 12 MiB [3072][2048]
  unsigned short* woT  = (unsigned short*)(ws + 29360128);    // 8 MiB
  float* qkv_f         = (float*)(ws + 37748736);             // 48 MiB [4096][3072]
  unsigned short* at_b = (unsigned short*)(ws + 37748736);    // aliases qkv_f (safe)
  unsigned short* q_b  = (unsigned short*)(ws + 88080384);    // 16 MiB
  unsigned short* k_b  = (unsigned short*)(ws + 104857600);   // 4 MiB
  unsigned short* vT_b = (unsigned short*)(ws + 109051904);   // 4 MiB

  const float qscale = 0.125f * 1.4426950408889634f;

  dim3 tb(32, 8);
  cast_bf16_kernel<<<8192, 256, 0, stream>>>(x, x_b, M_ * D_ / 4);
  transpose_cast_qkv_kernel<<<dim3(96, 64), tb, 0, stream>>>(wq, wk, wv, wT);
  transpose_cast_kernel<<<dim3(64, 64), tb, 0, stream>>>(wo, woT, 2048, 2048);

  gemm_bt_kernel<<<dim3(24, 32), 256, 0, stream>>>(x_b, wT, qkv_f, M_, NF_, 2048);

  rope_kernel<<<4096, 256, 0, stream>>>(qkv_f, fc, fs, q_b, 32, 0, qscale, M_ * 32 * 8);
  rope_kernel<<<1024, 256, 0, stream>>>(qkv_f, fc, fs, k_b, 8, 2048, 1.0f, M_ * 8 * 8);
  cast_vT_kernel<<<dim3(64, 2, 16), tb, 0, stream>>>(qkv_f, vT_b);

  attn_kernel<<<dim3(16, 64), 256, 0, stream>>>(q_b, k_b, vT_b, at_b);

  gemm_bt_kernel<<<dim3(16, 32), 256, 0, stream>>>(at_b, woT, out, M_, 2048, 2048);
}

// Round 9
// 387.378 us; speedup vs baseline: 1.1600x; 1.0413x over previous
//
#include <hip/hip_runtime.h>
#include <hip/hip_bf16.h>

#define B_   2
#define L_   2048
#define D_   2048
#define H_   32
#define HKV_ 8
#define HD_  64
#define G_   4
#define M_   4096   // B_*L_
#define NF_  3072   // fused QKV output width

typedef __attribute__((ext_vector_type(8))) short bf16x8;
typedef __attribute__((ext_vector_type(4))) float f32x4;

static __device__ __forceinline__ unsigned short f2bf(float f) {
  unsigned int u = __float_as_uint(f);
  unsigned int r = (u + 0x7FFFu + ((u >> 16) & 1u)) >> 16;
  return (unsigned short)r;
}
static __device__ __forceinline__ unsigned short f2bf_hw(float f) {
  __hip_bfloat16 h = __float2bfloat16(f);
  return *(unsigned short*)&h;
}

#define GLD16(g, l) __builtin_amdgcn_global_load_lds(                      \
    (const __attribute__((address_space(1))) void*)(g),                    \
    (__attribute__((address_space(3))) void*)(l), 16, 0, 0)

// ---------------- elementwise cast f32 -> bf16 (x4 vectorized) ----------------
__global__ void cast_bf16_kernel(const float* __restrict__ in,
                                 unsigned short* __restrict__ out, int n4) {
  int i = blockIdx.x * blockDim.x + threadIdx.x;
  if (i >= n4) return;
  float4 v = ((const float4*)in)[i];
  uint2 r;
  r.x = (unsigned int)f2bf(v.x) | ((unsigned int)f2bf(v.y) << 16);
  r.y = (unsigned int)f2bf(v.z) | ((unsigned int)f2bf(v.w) << 16);
  ((uint2*)out)[i] = r;
}

// ---------------- transpose+cast: src[K][N] f32 -> dst[N][K] bf16 ----------------
__global__ void transpose_cast_kernel(const float* __restrict__ src,
                                      unsigned short* __restrict__ dst,
                                      int K, int N) {
  __shared__ float tile[32][33];
  int k0 = blockIdx.y * 32, n0 = blockIdx.x * 32;
  int tx = threadIdx.x, ty = threadIdx.y;  // (32,8)
#pragma unroll
  for (int r = 0; r < 4; ++r)
    tile[ty * 4 + r][tx] = src[(size_t)(k0 + ty * 4 + r) * N + n0 + tx];
  __syncthreads();
#pragma unroll
  for (int r = 0; r < 4; ++r)
    dst[(size_t)(n0 + ty * 4 + r) * K + k0 + tx] = f2bf(tile[tx][ty * 4 + r]);
}

// ---------------- fused QKV weight transpose: wq/wk/wv -> wT[3072][2048] bf16 ----------------
__global__ void transpose_cast_qkv_kernel(const float* __restrict__ wq,
                                          const float* __restrict__ wk,
                                          const float* __restrict__ wv,
                                          unsigned short* __restrict__ dst) {
  __shared__ float tile[32][33];
  int n0 = blockIdx.x * 32, k0 = blockIdx.y * 32;
  const float* src;
  int ns, N;
  if (n0 < 2048)      { src = wq; ns = n0;        N = 2048; }
  else if (n0 < 2560) { src = wk; ns = n0 - 2048; N = 512; }
  else                { src = wv; ns = n0 - 2560; N = 512; }
  int tx = threadIdx.x, ty = threadIdx.y;  // (32,8)
#pragma unroll
  for (int r = 0; r < 4; ++r)
    tile[ty * 4 + r][tx] = src[(size_t)(k0 + ty * 4 + r) * N + ns + tx];
  __syncthreads();
#pragma unroll
  for (int r = 0; r < 4; ++r)
    dst[(size_t)(n0 + ty * 4 + r) * 2048 + k0 + tx] = f2bf(tile[tx][ty * 4 + r]);
}

// ---------------- GEMM 256x128: C[M][N] f32 = A[M][K]bf16 * Bt[N][K]bf16 ----------------
// BK=32, 8 waves (4M x 2N, 64x64 per wave), double-buffered LDS (48 KiB),
// issue-early staging + counted vmcnt(3) + raw s_barrier + setprio.
// 2x the MFMA per staged LDS byte of the 128^2 structure.
__global__ __launch_bounds__(512)
void gemm256x128_kernel(const unsigned short* __restrict__ A,
                        const unsigned short* __restrict__ Bt,
                        float* __restrict__ C, int M, int N, int K) {
  __shared__ unsigned short Al[2][256 * 32];
  __shared__ unsigned short Bl[2][128 * 32];
  const int tid = threadIdx.x;
  const int w = tid >> 6, l = tid & 63;
  const int wave_m = w >> 1, wave_n = w & 1;
  const int row0 = blockIdx.y * 256, col0 = blockIdx.x * 128;
  const int fr = l & 15, fk = (l >> 4) * 8;
  const int srow = l >> 2, scol = (l & 3) * 8;
  const int nk = K >> 5;

  f32x4 acc[4][4];
#pragma unroll
  for (int m = 0; m < 4; ++m)
#pragma unroll
    for (int n = 0; n < 4; ++n) acc[m][n] = (f32x4){0.f, 0.f, 0.f, 0.f};

#define GSTAGE(buf_, kt_) do {                                               \
    GLD16(A + (size_t)(row0 + w * 16 + srow) * K + (kt_) * 32 + scol,        \
          &Al[buf_][w * 512]);                                               \
    GLD16(A + (size_t)(row0 + 128 + w * 16 + srow) * K + (kt_) * 32 + scol,  \
          &Al[buf_][(8 + w) * 512]);                                         \
    GLD16(Bt + (size_t)(col0 + w * 16 + srow) * K + (kt_) * 32 + scol,       \
          &Bl[buf_][w * 512]);                                               \
  } while (0)

  GSTAGE(0, 0);  // prologue

  for (int kt = 0; kt < nk; ++kt) {
    const int buf = kt & 1;
    if (kt + 1 < nk) {
      GSTAGE(buf ^ 1, kt + 1);                           // issue-early
      asm volatile("s_waitcnt vmcnt(3)" ::: "memory");   // tile kt landed
    } else {
      asm volatile("s_waitcnt vmcnt(0)" ::: "memory");
    }
    __builtin_amdgcn_s_barrier();

    bf16x8 af[4], bfr[4];
#pragma unroll
    for (int m = 0; m < 4; ++m)
      af[m] = *(const bf16x8*)&Al[buf][(wave_m * 64 + m * 16 + fr) * 32 + fk];
#pragma unroll
    for (int n = 0; n < 4; ++n)
      bfr[n] = *(const bf16x8*)&Bl[buf][(wave_n * 64 + n * 16 + fr) * 32 + fk];
    __builtin_amdgcn_s_setprio(1);
#pragma unroll
    for (int m = 0; m < 4; ++m)
#pragma unroll
      for (int n = 0; n < 4; ++n)
        acc[m][n] = __builtin_amdgcn_mfma_f32_16x16x32_bf16(af[m], bfr[n], acc[m][n], 0, 0, 0);
    __builtin_amdgcn_s_setprio(0);
    __builtin_amdgcn_s_barrier();   // all waves done reading buf before overwrite
  }
#undef GSTAGE

  const int fq = l >> 4;
#pragma unroll
  for (int m = 0; m < 4; ++m)
#pragma unroll
    for (int n = 0; n < 4; ++n)
#pragma unroll
      for (int j = 0; j < 4; ++j) {
        int r = row0 + wave_m * 64 + m * 16 + fq * 4 + j;
        int c = col0 + wave_n * 64 + n * 16 + fr;
        C[(size_t)r * N + c] = acc[m][n][j];
      }
}

// ---------------- RoPE (float4-wide): src[M][3072]+col_off -> dst[B][nh][L][64] bf16 ----------------
__global__ void rope_kernel(const float* __restrict__ src,
                            const float* __restrict__ cosf,
                            const float* __restrict__ sinf,
                            unsigned short* __restrict__ dst, int nh, int col_off,
                            float scale, int total) {
  int idx = blockIdx.x * blockDim.x + threadIdx.x;
  if (idx >= total) return;
  int g = idx & 7;                  // group of 4 freqs (8 elements)
  int h = (idx >> 3) & (nh - 1);
  int row = idx / (nh << 3);
  int lpos = row & (L_ - 1);
  int b = row >> 11;
  const float* s = src + (size_t)row * NF_ + col_off + h * 64 + g * 8;
  float4 v0 = *(const float4*)s;
  float4 v1 = *(const float4*)(s + 4);
  float4 c4 = *(const float4*)(cosf + lpos * 32 + g * 4);
  float4 s4 = *(const float4*)(sinf + lpos * 32 + g * 4);
  float o0 = (v0.x * c4.x - v0.y * s4.x) * scale;
  float o1 = (v0.x * s4.x + v0.y * c4.x) * scale;
  float o2 = (v0.z * c4.y - v0.w * s4.y) * scale;
  float o3 = (v0.z * s4.y + v0.w * c4.y) * scale;
  float o4 = (v1.x * c4.z - v1.y * s4.z) * scale;
  float o5 = (v1.x * s4.z + v1.y * c4.z) * scale;
  float o6 = (v1.z * c4.w - v1.w * s4.w) * scale;
  float o7 = (v1.z * s4.w + v1.w * c4.w) * scale;
  uint4 r;
  r.x = (unsigned int)f2bf(o0) | ((unsigned int)f2bf(o1) << 16);
  r.y = (unsigned int)f2bf(o2) | ((unsigned int)f2bf(o3) << 16);
  r.z = (unsigned int)f2bf(o4) | ((unsigned int)f2bf(o5) << 16);
  r.w = (unsigned int)f2bf(o6) | ((unsigned int)f2bf(o7) << 16);
  *(uint4*)&dst[(((size_t)(b * nh + h)) * L_ + lpos) * 64 + g * 8] = r;
}

// ---------------- V transpose (LDS-tiled): qkv_f v-cols -> vT[B][HKV][64][L] bf16 ----------------
__global__ void cast_vT_kernel(const float* __restrict__ v,
                               unsigned short* __restrict__ vT) {
  __shared__ float tile[32][33];
  int l0 = blockIdx.x * 32, d0 = blockIdx.y * 32;
  int z = blockIdx.z;                 // b*8+hkv
  int b = z >> 3, hkv = z & 7;
  int tx = threadIdx.x, ty = threadIdx.y;  // (32,8)
  const float* src = v + (size_t)(b * L_) * NF_ + 2560 + hkv * 64;
#pragma unroll
  for (int r = 0; r < 4; ++r)
    tile[ty * 4 + r][tx] = src[(size_t)(l0 + ty * 4 + r) * NF_ + d0 + tx];
  __syncthreads();
  unsigned short* dst = vT + ((size_t)z * 64) * L_;
#pragma unroll
  for (int r = 0; r < 4; ++r)
    dst[(size_t)(d0 + ty * 4 + r) * L_ + l0 + tx] = f2bf(tile[tx][ty * 4 + r]);
}

// ---------------- Flash attention ----------------
// R3 structure (paired 128-row q-blocks {p,15-p}, 2 strips per staged tile, 512
// blocks, 34 tiles/block uniform) + R6 pipeline (double-buffered K/V,
// issue-early staging, counted vmcnt(4), raw s_barrier) + XCD chunk remap.
__global__ __launch_bounds__(256)
void attn_kernel(const unsigned short* __restrict__ Q,   // [B][H][L][64] (pre-scaled)
                 const unsigned short* __restrict__ Kt,  // [B][HKV][L][64]
                 const unsigned short* __restrict__ Vt,  // [B][HKV][64][L]
                 unsigned short* __restrict__ O) {       // [B*L][H*64]
  __shared__ unsigned short Kl[2][64 * 64];
  __shared__ unsigned short Vl[2][64 * 64];
  __shared__ unsigned short Pl[64 * 64];
  const int tid = threadIdx.x, w = tid >> 6, l = tid & 63;
  const int lin = blockIdx.y * 8 + blockIdx.x;      // grid (8 pair, 64 bh)
  const int work = ((lin & 7) << 6) + (lin >> 3);   // bijective XCD chunking (512/8=64)
  const int bh = work >> 3, pr = work & 7;
  const int b = bh >> 5, h = bh & 31;
  const int hkv = h >> 2;
  const int fr = l & 15, hi = l >> 4;
  const int frx = fr & 7;

  const int srow = l >> 3;
  const int scole = ((l & 7) ^ srow) * 8;   // pre-swizzled global source col

  const unsigned short* kbase = Kt + ((size_t)(b * HKV_ + hkv)) * L_ * 64;
  const unsigned short* vbase = Vt + ((size_t)(b * HKV_ + hkv)) * 64 * L_;

#define ASTAGE(kv0_, buf_) do {                                              \
    _Pragma("unroll")                                                        \
    for (int u_ = 0; u_ < 2; ++u_) {                                         \
      const int c_ = w * 2 + u_;                                             \
      const int rr_ = c_ * 8 + srow;                                         \
      GLD16(kbase + ((size_t)((kv0_) + rr_)) * 64 + scole,                   \
            &Kl[buf_][c_ * 512]);                                            \
      GLD16(vbase + ((size_t)rr_) * L_ + (kv0_) + scole,                     \
            &Vl[buf_][c_ * 512]);                                            \
    }                                                                        \
  } while (0)

  for (int half = 0; half < 2; ++half) {
    const int by = half ? (15 - pr) : pr;
    const int q0 = by * 128;

    bf16x8 qf[2][2];
#pragma unroll
    for (int s = 0; s < 2; ++s) {
      const unsigned short* qb =
          Q + (((size_t)bh) * L_ + q0 + s * 64 + w * 16 + fr) * 64 + hi * 8;
      qf[s][0] = *(const bf16x8*)(qb);
      qf[s][1] = *(const bf16x8*)(qb + 32);
    }

    float m_i[2][4], l_p[2][4];
    f32x4 oacc[2][4];
#pragma unroll
    for (int s = 0; s < 2; ++s)
#pragma unroll
      for (int j = 0; j < 4; ++j) { m_i[s][j] = -1e30f; l_p[s][j] = 0.f; }
#pragma unroll
    for (int s = 0; s < 2; ++s)
#pragma unroll
      for (int nf = 0; nf < 4; ++nf) oacc[s][nf] = (f32x4){0.f, 0.f, 0.f, 0.f};

    const int nt = 2 * by + 2;

    ASTAGE(0, 0);   // per-half prologue (4 loads/wave)

    for (int t = 0; t < nt; ++t) {
      const int buf = t & 1;
      if (t + 1 < nt) {
        ASTAGE((t + 1) * 64, buf ^ 1);                     // issue-early
        asm volatile("s_waitcnt vmcnt(4)" ::: "memory");   // tile t landed
      } else {
        asm volatile("s_waitcnt vmcnt(0)" ::: "memory");
      }
      __builtin_amdgcn_s_barrier();

      const int kv0 = t * 64;
#pragma unroll
      for (int s = 0; s < 2; ++s) {
        const int dlim = 2 * by + s;
        if (t > dlim) continue;   // strip fully masked (uniform; only t=nt-1,s=0)

        f32x4 sacc[4];
#pragma unroll
        for (int nf = 0; nf < 4; ++nf) sacc[nf] = (f32x4){0.f, 0.f, 0.f, 0.f};
        __builtin_amdgcn_s_setprio(1);
#pragma unroll
        for (int ks = 0; ks < 2; ++ks) {
#pragma unroll
          for (int nf = 0; nf < 4; ++nf) {
            bf16x8 kfrag = *(const bf16x8*)
                &Kl[buf][(nf * 16 + fr) * 64 + (((ks * 4 + hi) ^ frx) * 8)];
            sacc[nf] = __builtin_amdgcn_mfma_f32_16x16x32_bf16(qf[s][ks], kfrag, sacc[nf], 0, 0, 0);
          }
        }
        __builtin_amdgcn_s_setprio(0);

        if (t == dlim) {
          const int rbase = q0 + s * 64 + w * 16 + hi * 4;
#pragma unroll
          for (int nf = 0; nf < 4; ++nf)
#pragma unroll
            for (int j = 0; j < 4; ++j)
              if (kv0 + nf * 16 + fr > rbase + j) sacc[nf][j] = -1e30f;
        }

        float rowmax[4];
#pragma unroll
        for (int j = 0; j < 4; ++j) {
          float mx = fmaxf(fmaxf(sacc[0][j], sacc[1][j]),
                           fmaxf(sacc[2][j], sacc[3][j]));
          mx = fmaxf(mx, __shfl_xor(mx, 1));
          mx = fmaxf(mx, __shfl_xor(mx, 2));
          mx = fmaxf(mx, __shfl_xor(mx, 4));
          mx = fmaxf(mx, __shfl_xor(mx, 8));
          rowmax[j] = mx;
        }

        float g = rowmax[0] - m_i[s][0];
        g = fmaxf(g, rowmax[1] - m_i[s][1]);
        g = fmaxf(g, rowmax[2] - m_i[s][2]);
        g = fmaxf(g, rowmax[3] - m_i[s][3]);
        if (!__all(g <= 8.f)) {
#pragma unroll
          for (int j = 0; j < 4; ++j) {
            float mnew = fmaxf(m_i[s][j], rowmax[j]);
            float cr = exp2f(m_i[s][j] - mnew);
            m_i[s][j] = mnew;
            l_p[s][j] *= cr;
#pragma unroll
            for (int nf = 0; nf < 4; ++nf) oacc[s][nf][j] *= cr;
          }
        }

#pragma unroll
        for (int j = 0; j < 4; ++j) {
          const int prow = w * 16 + hi * 4 + j;
#pragma unroll
          for (int nf = 0; nf < 4; ++nf) {
            float pv = exp2f(sacc[nf][j] - m_i[s][j]);
            l_p[s][j] += pv;
            Pl[prow * 64 + (((nf * 2 + (fr >> 3)) ^ (prow & 7)) * 8) + frx] =
                f2bf_hw(pv);
          }
        }

        __builtin_amdgcn_s_setprio(1);
#pragma unroll
        for (int ks = 0; ks < 2; ++ks) {
          bf16x8 pa = *(const bf16x8*)
              &Pl[(w * 16 + fr) * 64 + (((ks * 4 + hi) ^ frx) * 8)];
#pragma unroll
          for (int nf = 0; nf < 4; ++nf) {
            bf16x8 vfrag = *(const bf16x8*)
                &Vl[buf][(nf * 16 + fr) * 64 + (((ks * 4 + hi) ^ frx) * 8)];
            oacc[s][nf] = __builtin_amdgcn_mfma_f32_16x16x32_bf16(pa, vfrag, oacc[s][nf], 0, 0, 0);
          }
        }
        __builtin_amdgcn_s_setprio(0);
      }
      __builtin_amdgcn_s_barrier();   // guard buf reuse by next tile's ASTAGE
    }

    // per-half epilogue
#pragma unroll
    for (int s = 0; s < 2; ++s)
#pragma unroll
      for (int j = 0; j < 4; ++j) {
        float lsum = l_p[s][j];
        lsum += __shfl_xor(lsum, 1);
        lsum += __shfl_xor(lsum, 2);
        lsum += __shfl_xor(lsum, 4);
        lsum += __shfl_xor(lsum, 8);
        float inv = 1.0f / lsum;
#pragma unroll
        for (int nf = 0; nf < 4; ++nf) {
          int qrow = q0 + s * 64 + w * 16 + hi * 4 + j;
          int d = nf * 16 + fr;
          O[((size_t)(b * L_ + qrow)) * 2048 + h * 64 + d] =
              f2bf_hw(oacc[s][nf][j] * inv);
        }
      }
  }
#undef ASTAGE
}

extern "C" void kernel_launch(void* const* d_in, const int* in_sizes, int n_in,
                              void* d_out, int out_size, void* d_ws, size_t ws_size,
                              hipStream_t stream) {
  (void)in_sizes; (void)n_in; (void)out_size; (void)ws_size;
  const float* x  = (const float*)d_in[0];
  const float* wq = (const float*)d_in[1];
  const float* wk = (const float*)d_in[2];
  const float* wv = (const float*)d_in[3];
  const float* wo = (const float*)d_in[4];
  const float* fc = (const float*)d_in[5];
  const float* fs = (const float*)d_in[6];
  float* out = (float*)d_out;

  char* ws = (char*)d_ws;
  unsigned short* x_b  = (unsigned short*)(ws + 0);           // 16 MiB
  unsigned short* wT   = (unsigned short*)(ws + 16777216);    // 12 MiB [3072][2048]
  unsigned short* woT  = (unsigned short*)(ws + 29360128);    // 8 MiB
  float* qkv_f         = (float*)(ws + 37748736);             // 48 MiB [4096][3072]
  unsigned short* at_b = (unsigned short*)(ws + 37748736);    // aliases qkv_f (safe)
  unsigned short* q_b  = (unsigned short*)(ws + 88080384);    // 16 MiB
  unsigned short* k_b  = (unsigned short*)(ws + 104857600);   // 4 MiB
  unsigned short* vT_b = (unsigned short*)(ws + 109051904);   // 4 MiB

  const float qscale = 0.125f * 1.4426950408889634f;

  dim3 tb(32, 8);
  cast_bf16_kernel<<<8192, 256, 0, stream>>>(x, x_b, M_ * D_ / 4);
  transpose_cast_qkv_kernel<<<dim3(96, 64), tb, 0, stream>>>(wq, wk, wv, wT);
  transpose_cast_kernel<<<dim3(64, 64), tb, 0, stream>>>(wo, woT, 2048, 2048);

  gemm256x128_kernel<<<dim3(NF_ / 128, M_ / 256), 512, 0, stream>>>(
      x_b, wT, qkv_f, M_, NF_, 2048);

  rope_kernel<<<4096, 256, 0, stream>>>(qkv_f, fc, fs, q_b, 32, 0, qscale, M_ * 32 * 8);
  rope_kernel<<<1024, 256, 0, stream>>>(qkv_f, fc, fs, k_b, 8, 2048, 1.0f, M_ * 8 * 8);
  cast_vT_kernel<<<dim3(64, 2, 16), tb, 0, stream>>>(qkv_f, vT_b);

  attn_kernel<<<dim3(8, 64), 256, 0, stream>>>(q_b, k_b, vT_b, at_b);

  gemm256x128_kernel<<<dim3(2048 / 128, M_ / 256), 512, 0, stream>>>(
      at_b, woT, out, M_, 2048, 2048);
}

// Round 10
// 379.412 us; speedup vs baseline: 1.1844x; 1.0210x over previous
//
#include <hip/hip_runtime.h>
#include <hip/hip_bf16.h>

#define B_   2
#define L_   2048
#define D_   2048
#define H_   32
#define HKV_ 8
#define HD_  64
#define G_   4
#define M_   4096   // B_*L_
#define NF_  3072   // fused QKV output width

typedef __attribute__((ext_vector_type(8))) short bf16x8;
typedef __attribute__((ext_vector_type(4))) float f32x4;

static __device__ __forceinline__ unsigned short f2bf(float f) {
  unsigned int u = __float_as_uint(f);
  unsigned int r = (u + 0x7FFFu + ((u >> 16) & 1u)) >> 16;
  return (unsigned short)r;
}
static __device__ __forceinline__ unsigned short f2bf_hw(float f) {
  __hip_bfloat16 h = __float2bfloat16(f);
  return *(unsigned short*)&h;
}
static __device__ __forceinline__ float bf2f(unsigned short u) {
  return __uint_as_float(((unsigned int)u) << 16);
}

#define GLD16(g, l) __builtin_amdgcn_global_load_lds(                      \
    (const __attribute__((address_space(1))) void*)(g),                    \
    (__attribute__((address_space(3))) void*)(l), 16, 0, 0)

// ---------------- elementwise cast f32 -> bf16 (x4 vectorized) ----------------
__global__ void cast_bf16_kernel(const float* __restrict__ in,
                                 unsigned short* __restrict__ out, int n4) {
  int i = blockIdx.x * blockDim.x + threadIdx.x;
  if (i >= n4) return;
  float4 v = ((const float4*)in)[i];
  uint2 r;
  r.x = (unsigned int)f2bf(v.x) | ((unsigned int)f2bf(v.y) << 16);
  r.y = (unsigned int)f2bf(v.z) | ((unsigned int)f2bf(v.w) << 16);
  ((uint2*)out)[i] = r;
}

// ---------------- transpose+cast: src[K][N] f32 -> dst[N][K] bf16 ----------------
__global__ void transpose_cast_kernel(const float* __restrict__ src,
                                      unsigned short* __restrict__ dst,
                                      int K, int N) {
  __shared__ float tile[32][33];
  int k0 = blockIdx.y * 32, n0 = blockIdx.x * 32;
  int tx = threadIdx.x, ty = threadIdx.y;  // (32,8)
#pragma unroll
  for (int r = 0; r < 4; ++r)
    tile[ty * 4 + r][tx] = src[(size_t)(k0 + ty * 4 + r) * N + n0 + tx];
  __syncthreads();
#pragma unroll
  for (int r = 0; r < 4; ++r)
    dst[(size_t)(n0 + ty * 4 + r) * K + k0 + tx] = f2bf(tile[tx][ty * 4 + r]);
}

// ---------------- fused QKV weight transpose: wq/wk/wv -> wT[3072][2048] bf16 ----------------
__global__ void transpose_cast_qkv_kernel(const float* __restrict__ wq,
                                          const float* __restrict__ wk,
                                          const float* __restrict__ wv,
                                          unsigned short* __restrict__ dst) {
  __shared__ float tile[32][33];
  int n0 = blockIdx.x * 32, k0 = blockIdx.y * 32;
  const float* src;
  int ns, N;
  if (n0 < 2048)      { src = wq; ns = n0;        N = 2048; }
  else if (n0 < 2560) { src = wk; ns = n0 - 2048; N = 512; }
  else                { src = wv; ns = n0 - 2560; N = 512; }
  int tx = threadIdx.x, ty = threadIdx.y;  // (32,8)
#pragma unroll
  for (int r = 0; r < 4; ++r)
    tile[ty * 4 + r][tx] = src[(size_t)(k0 + ty * 4 + r) * N + ns + tx];
  __syncthreads();
#pragma unroll
  for (int r = 0; r < 4; ++r)
    dst[(size_t)(n0 + ty * 4 + r) * 2048 + k0 + tx] = f2bf(tile[tx][ty * 4 + r]);
}

// ---------------- GEMM 256x128: C[M][N] = A[M][K]bf16 * Bt[N][K]bf16 ----------------
// BK=32, 8 waves (4M x 2N, 64x64 per wave), double-buffered LDS (48 KiB),
// issue-early staging + counted vmcnt(3) + raw s_barrier + setprio.
// OUT_T: unsigned short (bf16 epilogue cast) or float.
template <typename OUT_T>
__global__ __launch_bounds__(512)
void gemm256x128_kernel(const unsigned short* __restrict__ A,
                        const unsigned short* __restrict__ Bt,
                        OUT_T* __restrict__ C, int M, int N, int K) {
  __shared__ unsigned short Al[2][256 * 32];
  __shared__ unsigned short Bl[2][128 * 32];
  const int tid = threadIdx.x;
  const int w = tid >> 6, l = tid & 63;
  const int wave_m = w >> 1, wave_n = w & 1;
  const int row0 = blockIdx.y * 256, col0 = blockIdx.x * 128;
  const int fr = l & 15, fk = (l >> 4) * 8;
  const int srow = l >> 2, scol = (l & 3) * 8;
  const int nk = K >> 5;

  f32x4 acc[4][4];
#pragma unroll
  for (int m = 0; m < 4; ++m)
#pragma unroll
    for (int n = 0; n < 4; ++n) acc[m][n] = (f32x4){0.f, 0.f, 0.f, 0.f};

#define GSTAGE(buf_, kt_) do {                                               \
    GLD16(A + (size_t)(row0 + w * 16 + srow) * K + (kt_) * 32 + scol,        \
          &Al[buf_][w * 512]);                                               \
    GLD16(A + (size_t)(row0 + 128 + w * 16 + srow) * K + (kt_) * 32 + scol,  \
          &Al[buf_][(8 + w) * 512]);                                         \
    GLD16(Bt + (size_t)(col0 + w * 16 + srow) * K + (kt_) * 32 + scol,       \
          &Bl[buf_][w * 512]);                                               \
  } while (0)

  GSTAGE(0, 0);  // prologue

  for (int kt = 0; kt < nk; ++kt) {
    const int buf = kt & 1;
    if (kt + 1 < nk) {
      GSTAGE(buf ^ 1, kt + 1);                           // issue-early
      asm volatile("s_waitcnt vmcnt(3)" ::: "memory");   // tile kt landed
    } else {
      asm volatile("s_waitcnt vmcnt(0)" ::: "memory");
    }
    __builtin_amdgcn_s_barrier();

    bf16x8 af[4], bfr[4];
#pragma unroll
    for (int m = 0; m < 4; ++m)
      af[m] = *(const bf16x8*)&Al[buf][(wave_m * 64 + m * 16 + fr) * 32 + fk];
#pragma unroll
    for (int n = 0; n < 4; ++n)
      bfr[n] = *(const bf16x8*)&Bl[buf][(wave_n * 64 + n * 16 + fr) * 32 + fk];
    __builtin_amdgcn_s_setprio(1);
#pragma unroll
    for (int m = 0; m < 4; ++m)
#pragma unroll
      for (int n = 0; n < 4; ++n)
        acc[m][n] = __builtin_amdgcn_mfma_f32_16x16x32_bf16(af[m], bfr[n], acc[m][n], 0, 0, 0);
    __builtin_amdgcn_s_setprio(0);
    __builtin_amdgcn_s_barrier();   // all waves done reading buf before overwrite
  }
#undef GSTAGE

  const int fq = l >> 4;
#pragma unroll
  for (int m = 0; m < 4; ++m)
#pragma unroll
    for (int n = 0; n < 4; ++n)
#pragma unroll
      for (int j = 0; j < 4; ++j) {
        int r = row0 + wave_m * 64 + m * 16 + fq * 4 + j;
        int c = col0 + wave_n * 64 + n * 16 + fr;
        if constexpr (sizeof(OUT_T) == 2)
          C[(size_t)r * N + c] = f2bf_hw(acc[m][n][j]);
        else
          C[(size_t)r * N + c] = acc[m][n][j];
      }
}

// ---------------- RoPE (bf16-in, 16B/lane): src[M][3072]bf16+col_off -> dst[B][nh][L][64] bf16 ----------------
__global__ void rope_kernel(const unsigned short* __restrict__ src,
                            const float* __restrict__ cosf,
                            const float* __restrict__ sinf,
                            unsigned short* __restrict__ dst, int nh, int col_off,
                            float scale, int total) {
  int idx = blockIdx.x * blockDim.x + threadIdx.x;
  if (idx >= total) return;
  int g = idx & 7;                  // group of 4 freqs (8 elements)
  int h = (idx >> 3) & (nh - 1);
  int row = idx / (nh << 3);
  int lpos = row & (L_ - 1);
  int b = row >> 11;
  bf16x8 v = *(const bf16x8*)(src + (size_t)row * NF_ + col_off + h * 64 + g * 8);
  float4 c4 = *(const float4*)(cosf + lpos * 32 + g * 4);
  float4 s4 = *(const float4*)(sinf + lpos * 32 + g * 4);
  float e0 = bf2f((unsigned short)v[0]), e1 = bf2f((unsigned short)v[1]);
  float e2 = bf2f((unsigned short)v[2]), e3 = bf2f((unsigned short)v[3]);
  float e4 = bf2f((unsigned short)v[4]), e5 = bf2f((unsigned short)v[5]);
  float e6 = bf2f((unsigned short)v[6]), e7 = bf2f((unsigned short)v[7]);
  float o0 = (e0 * c4.x - e1 * s4.x) * scale;
  float o1 = (e0 * s4.x + e1 * c4.x) * scale;
  float o2 = (e2 * c4.y - e3 * s4.y) * scale;
  float o3 = (e2 * s4.y + e3 * c4.y) * scale;
  float o4 = (e4 * c4.z - e5 * s4.z) * scale;
  float o5 = (e4 * s4.z + e5 * c4.z) * scale;
  float o6 = (e6 * c4.w - e7 * s4.w) * scale;
  float o7 = (e6 * s4.w + e7 * c4.w) * scale;
  uint4 r;
  r.x = (unsigned int)f2bf(o0) | ((unsigned int)f2bf(o1) << 16);
  r.y = (unsigned int)f2bf(o2) | ((unsigned int)f2bf(o3) << 16);
  r.z = (unsigned int)f2bf(o4) | ((unsigned int)f2bf(o5) << 16);
  r.w = (unsigned int)f2bf(o6) | ((unsigned int)f2bf(o7) << 16);
  *(uint4*)&dst[(((size_t)(b * nh + h)) * L_ + lpos) * 64 + g * 8] = r;
}

// ---------------- V transpose (LDS-tiled, bf16-in): qkv_b v-cols -> vT[B][HKV][64][L] bf16 ----------------
__global__ void cast_vT_kernel(const unsigned short* __restrict__ v,
                               unsigned short* __restrict__ vT) {
  __shared__ unsigned short tile[32][33];
  int l0 = blockIdx.x * 32, d0 = blockIdx.y * 32;
  int z = blockIdx.z;                 // b*8+hkv
  int b = z >> 3, hkv = z & 7;
  int tx = threadIdx.x, ty = threadIdx.y;  // (32,8)
  const unsigned short* src = v + (size_t)(b * L_) * NF_ + 2560 + hkv * 64;
#pragma unroll
  for (int r = 0; r < 4; ++r)
    tile[ty * 4 + r][tx] = src[(size_t)(l0 + ty * 4 + r) * NF_ + d0 + tx];
  __syncthreads();
  unsigned short* dst = vT + ((size_t)z * 64) * L_;
#pragma unroll
  for (int r = 0; r < 4; ++r)
    dst[(size_t)(d0 + ty * 4 + r) * L_ + l0 + tx] = tile[tx][ty * 4 + r];
}

// ---------------- Flash attention (measured-best R4 body + XCD chunk remap) ----------------
// Paired 128-row q-blocks {p,15-p} per (b,h): 34 tiles/block uniform. Single-buffer
// K/V, __syncthreads, setprio around MFMA. Grid (8,64) = 512 blocks, remapped so
// each XCD's L2 holds K/V of only 2 (b,hkv) sets.
__global__ __launch_bounds__(256)
void attn_kernel(const unsigned short* __restrict__ Q,   // [B][H][L][64] (pre-scaled)
                 const unsigned short* __restrict__ Kt,  // [B][HKV][L][64]
                 const unsigned short* __restrict__ Vt,  // [B][HKV][64][L]
                 unsigned short* __restrict__ O) {       // [B*L][H*64]
  __shared__ unsigned short Kl[64 * 64];
  __shared__ unsigned short Vl[64 * 64];
  __shared__ unsigned short Pl[64 * 64];
  const int tid = threadIdx.x, w = tid >> 6, l = tid & 63;
  const int lin = blockIdx.y * 8 + blockIdx.x;      // grid (8,64)
  const int work = ((lin & 7) << 6) + (lin >> 3);   // bijective XCD chunking
  const int bh = work >> 3, pair = work & 7;
  const int b = bh >> 5, h = bh & 31;
  const int hkv = h >> 2;
  const int fr = l & 15, hi = l >> 4;
  const int frx = fr & 7;

  const int srow = l >> 3;
  const int scole = ((l & 7) ^ srow) * 8;   // pre-swizzled global source col

  const unsigned short* kbase = Kt + ((size_t)(b * HKV_ + hkv)) * L_ * 64;
  const unsigned short* vbase = Vt + ((size_t)(b * HKV_ + hkv)) * 64 * L_;

  for (int half = 0; half < 2; ++half) {
    const int by = half ? (15 - pair) : pair;
    const int q0 = by * 128;

    bf16x8 qf[2][2];
#pragma unroll
    for (int s = 0; s < 2; ++s) {
      const unsigned short* qb =
          Q + (((size_t)bh) * L_ + q0 + s * 64 + w * 16 + fr) * 64 + hi * 8;
      qf[s][0] = *(const bf16x8*)(qb);
      qf[s][1] = *(const bf16x8*)(qb + 32);
    }

    float m_i[2][4], l_p[2][4];
    f32x4 oacc[2][4];
#pragma unroll
    for (int s = 0; s < 2; ++s)
#pragma unroll
      for (int j = 0; j < 4; ++j) { m_i[s][j] = -1e30f; l_p[s][j] = 0.f; }
#pragma unroll
    for (int s = 0; s < 2; ++s)
#pragma unroll
      for (int nf = 0; nf < 4; ++nf) oacc[s][nf] = (f32x4){0.f, 0.f, 0.f, 0.f};

    const int nt = 2 * by + 2;

    for (int t = 0; t < nt; ++t) {
      const int kv0 = t * 64;
#pragma unroll
      for (int u = 0; u < 2; ++u) {
        const int c = w * 2 + u;
        const int rr = c * 8 + srow;
        GLD16(kbase + ((size_t)(kv0 + rr)) * 64 + scole, &Kl[c * 512]);
        GLD16(vbase + ((size_t)rr) * L_ + kv0 + scole, &Vl[c * 512]);
      }
      __syncthreads();

#pragma unroll
      for (int s = 0; s < 2; ++s) {
        const int dlim = 2 * by + s;
        if (t > dlim) continue;

        f32x4 sacc[4];
#pragma unroll
        for (int nf = 0; nf < 4; ++nf) sacc[nf] = (f32x4){0.f, 0.f, 0.f, 0.f};
        __builtin_amdgcn_s_setprio(1);
#pragma unroll
        for (int ks = 0; ks < 2; ++ks) {
#pragma unroll
          for (int nf = 0; nf < 4; ++nf) {
            bf16x8 kfrag = *(const bf16x8*)
                &Kl[(nf * 16 + fr) * 64 + (((ks * 4 + hi) ^ frx) * 8)];
            sacc[nf] = __builtin_amdgcn_mfma_f32_16x16x32_bf16(qf[s][ks], kfrag, sacc[nf], 0, 0, 0);
          }
        }
        __builtin_amdgcn_s_setprio(0);

        if (t == dlim) {
          const int rbase = q0 + s * 64 + w * 16 + hi * 4;
#pragma unroll
          for (int nf = 0; nf < 4; ++nf)
#pragma unroll
            for (int j = 0; j < 4; ++j)
              if (kv0 + nf * 16 + fr > rbase + j) sacc[nf][j] = -1e30f;
        }

        float rowmax[4];
#pragma unroll
        for (int j = 0; j < 4; ++j) {
          float mx = fmaxf(fmaxf(sacc[0][j], sacc[1][j]),
                           fmaxf(sacc[2][j], sacc[3][j]));
          mx = fmaxf(mx, __shfl_xor(mx, 1));
          mx = fmaxf(mx, __shfl_xor(mx, 2));
          mx = fmaxf(mx, __shfl_xor(mx, 4));
          mx = fmaxf(mx, __shfl_xor(mx, 8));
          rowmax[j] = mx;
        }

        float g = rowmax[0] - m_i[s][0];
        g = fmaxf(g, rowmax[1] - m_i[s][1]);
        g = fmaxf(g, rowmax[2] - m_i[s][2]);
        g = fmaxf(g, rowmax[3] - m_i[s][3]);
        if (!__all(g <= 8.f)) {
#pragma unroll
          for (int j = 0; j < 4; ++j) {
            float mnew = fmaxf(m_i[s][j], rowmax[j]);
            float cr = exp2f(m_i[s][j] - mnew);
            m_i[s][j] = mnew;
            l_p[s][j] *= cr;
#pragma unroll
            for (int nf = 0; nf < 4; ++nf) oacc[s][nf][j] *= cr;
          }
        }

#pragma unroll
        for (int j = 0; j < 4; ++j) {
          const int prow = w * 16 + hi * 4 + j;
#pragma unroll
          for (int nf = 0; nf < 4; ++nf) {
            float pv = exp2f(sacc[nf][j] - m_i[s][j]);
            l_p[s][j] += pv;
            Pl[prow * 64 + (((nf * 2 + (fr >> 3)) ^ (prow & 7)) * 8) + frx] =
                f2bf_hw(pv);
          }
        }

        __builtin_amdgcn_s_setprio(1);
#pragma unroll
        for (int ks = 0; ks < 2; ++ks) {
          bf16x8 pa = *(const bf16x8*)
              &Pl[(w * 16 + fr) * 64 + (((ks * 4 + hi) ^ frx) * 8)];
#pragma unroll
          for (int nf = 0; nf < 4; ++nf) {
            bf16x8 vfrag = *(const bf16x8*)
                &Vl[(nf * 16 + fr) * 64 + (((ks * 4 + hi) ^ frx) * 8)];
            oacc[s][nf] = __builtin_amdgcn_mfma_f32_16x16x32_bf16(pa, vfrag, oacc[s][nf], 0, 0, 0);
          }
        }
        __builtin_amdgcn_s_setprio(0);
      }
      __syncthreads();
    }

#pragma unroll
    for (int s = 0; s < 2; ++s)
#pragma unroll
      for (int j = 0; j < 4; ++j) {
        float lsum = l_p[s][j];
        lsum += __shfl_xor(lsum, 1);
        lsum += __shfl_xor(lsum, 2);
        lsum += __shfl_xor(lsum, 4);
        lsum += __shfl_xor(lsum, 8);
        float inv = 1.0f / lsum;
#pragma unroll
        for (int nf = 0; nf < 4; ++nf) {
          int qrow = q0 + s * 64 + w * 16 + hi * 4 + j;
          int d = nf * 16 + fr;
          O[((size_t)(b * L_ + qrow)) * 2048 + h * 64 + d] =
              f2bf_hw(oacc[s][nf][j] * inv);
        }
      }
  }
}

extern "C" void kernel_launch(void* const* d_in, const int* in_sizes, int n_in,
                              void* d_out, int out_size, void* d_ws, size_t ws_size,
                              hipStream_t stream) {
  (void)in_sizes; (void)n_in; (void)out_size; (void)ws_size;
  const float* x  = (const float*)d_in[0];
  const float* wq = (const float*)d_in[1];
  const float* wk = (const float*)d_in[2];
  const float* wv = (const float*)d_in[3];
  const float* wo = (const float*)d_in[4];
  const float* fc = (const float*)d_in[5];
  const float* fs = (const float*)d_in[6];
  float* out = (float*)d_out;

  char* ws = (char*)d_ws;
  unsigned short* x_b   = (unsigned short*)(ws + 0);           // 16 MiB
  unsigned short* wT    = (unsigned short*)(ws + 16777216);    // 12 MiB [3072][2048]
  unsigned short* woT   = (unsigned short*)(ws + 29360128);    // 8 MiB
  unsigned short* qkv_b = (unsigned short*)(ws + 37748736);    // 24 MiB [4096][3072] bf16
  unsigned short* at_b  = (unsigned short*)(ws + 62914560);    // 16 MiB [4096][2048] bf16
  unsigned short* q_b   = (unsigned short*)(ws + 88080384);    // 16 MiB
  unsigned short* k_b   = (unsigned short*)(ws + 104857600);   // 4 MiB
  unsigned short* vT_b  = (unsigned short*)(ws + 109051904);   // 4 MiB

  // 0.125 (1/sqrt(64)) * log2(e): QK^T lands directly in exp2 domain.
  const float qscale = 0.125f * 1.4426950408889634f;

  dim3 tb(32, 8);
  cast_bf16_kernel<<<8192, 256, 0, stream>>>(x, x_b, M_ * D_ / 4);
  transpose_cast_qkv_kernel<<<dim3(96, 64), tb, 0, stream>>>(wq, wk, wv, wT);
  transpose_cast_kernel<<<dim3(64, 64), tb, 0, stream>>>(wo, woT, 2048, 2048);

  gemm256x128_kernel<unsigned short><<<dim3(NF_ / 128, M_ / 256), 512, 0, stream>>>(
      x_b, wT, qkv_b, M_, NF_, 2048);

  rope_kernel<<<4096, 256, 0, stream>>>(qkv_b, fc, fs, q_b, 32, 0, qscale, M_ * 32 * 8);
  rope_kernel<<<1024, 256, 0, stream>>>(qkv_b, fc, fs, k_b, 8, 2048, 1.0f, M_ * 8 * 8);
  cast_vT_kernel<<<dim3(64, 2, 16), tb, 0, stream>>>(qkv_b, vT_b);

  attn_kernel<<<dim3(8, 64), 256, 0, stream>>>(q_b, k_b, vT_b, at_b);

  gemm256x128_kernel<float><<<dim3(2048 / 128, M_ / 256), 512, 0, stream>>>(
      at_b, woT, out, M_, 2048, 2048);
}